// Round 14
// baseline (780.748 us; speedup 1.0000x reference)
//
#include <hip/hip_runtime.h>
#include <hip/hip_fp16.h>

#define HDIM  50
#define G3    150
#define TSEQ  512
#define BATCH 2048
#define NB    8        // real batches per block (MFMA cols 0..7; 8..15 mirror col 7)
#define NLAY  4
#define NT    12       // A-row tiles: 0-3 = r, 4-7 = z, 8-11 = n (50 real rows / 64)

typedef _Float16 f16x8 __attribute__((ext_vector_type(8)));
typedef float    f32x4 __attribute__((ext_vector_type(4)));

#define MFMA(a,b,c) __builtin_amdgcn_mfma_f32_16x16x32_f16((a),(b),(c),0,0,0)

static __device__ inline unsigned pk2(float a, float b) {
    return __builtin_bit_cast(unsigned, __builtin_amdgcn_cvt_pkrtz(a, b));
}
static __device__ inline float rcpf(float x) { return __builtin_amdgcn_rcpf(x); }

// raw v_exp_f32 (exp2), no ocml wrapper
#if __has_builtin(__builtin_amdgcn_exp2f)
static __device__ inline float ex2(float x) { return __builtin_amdgcn_exp2f(x); }
#else
static __device__ inline float ex2(float x) {
    float r; asm volatile("v_exp_f32 %0, %1" : "=v"(r) : "v"(x)); return r;
}
#endif
// lane swizzle xor 8 (BitMode offset 0x201F)
static __device__ inline float swz8(float x) {
    return __builtin_bit_cast(float,
        __builtin_amdgcn_ds_swizzle(__builtin_bit_cast(int, x), 0x201F));
}

// Weight pre-scaling folded at fragment load:
//   r,z columns * -log2(e):  sigmoid(g) = rcp(1 + exp2(acc))
//   n  columns * +2*log2(e): tanh(v)    = 1 - 2*rcp(exp2(acc) + 1)
#define SCL_RZ (-1.44269504f)
#define SCL_N  ( 2.88539008f)

// r10 skeleton: wave = layer, all 3 gates in-wave (tile-aligned), one barrier
// per pipeline step, parity double-buffered LDS handoff. New: native exp2 +
// lane-pair-shared evals (lanes lb>=8 are mirror cols -> they evaluate the
// partner lane's second value instead; results swapped back via ds_swizzle).
__global__ __launch_bounds__(256, 1)
void gru_fused1w(const float* __restrict__ xin,
                 const float* __restrict__ Wih0, const float* __restrict__ Whh0,
                 const float* __restrict__ bih0, const float* __restrict__ bhh0,
                 const float* __restrict__ WihL, const float* __restrict__ WhhL,
                 const float* __restrict__ bihL, const float* __restrict__ bhhL,
                 const float* __restrict__ fcw,  const float* __restrict__ fcb,
                 float* __restrict__ out)
{
    const int tid  = threadIdx.x;
    const int lay  = tid >> 6;
    const int lane = tid & 63;
    const int lb   = lane & 15;
    const int lg   = lane >> 4;
    const int b0   = blockIdx.x * NB;
    const int lbc  = (lb < NB) ? lb : (NB - 1);
    const bool lo  = (lb < 8);

    __shared__ __align__(16) _Float16 h_lds[NLAY][2][16][72];  // k=50 = const 1.0
    __shared__ float x_row[NB][516];

    const float* Wih = (lay==0) ? Wih0 : WihL + (size_t)(lay-1)*G3*HDIM;
    const float* Whh = (lay==0) ? Whh0 : WhhL + (size_t)(lay-1)*G3*HDIM;
    const float* bih = (lay==0) ? bih0 : bihL + (lay-1)*G3;
    const float* bhh = (lay==0) ? bhh0 : bhhL + (lay-1)*G3;

    // ---- A fragments; biases folded at k==50; transcendental scale folded ----
    f16x8 a_hh[NT][2], a_ih[NT][2];
#pragma unroll
    for (int mt = 0; mt < NT; ++mt) {
        const int  ur = (mt & 3)*16 + lb;
        const bool rv = ur < HDIM;
        const int  gr = 50*(mt >> 2) + (rv ? ur : 0);
        const float scl = (mt < 8) ? SCL_RZ : SCL_N;
#pragma unroll
        for (int kt = 0; kt < 2; ++kt) {
            f16x8 fh, fi;
#pragma unroll
            for (int j = 0; j < 8; ++j) {
                const int k = 32*kt + 8*lg + j;
                float vh = 0.f, vi = 0.f;
                if (rv) {
                    if (k < HDIM)       vh = Whh[gr*HDIM + k];
                    else if (k == HDIM) vh = bhh[gr];
                    if (lay == 0) {
                        if (kt == 0 && k == 0)      vi = Wih[gr];
                        else if (kt == 0 && k == 1) vi = bih[gr];
                    } else {
                        if (k < HDIM)       vi = Wih[gr*HDIM + k];
                        else if (k == HDIM) vi = bih[gr];
                    }
                }
                fh[j] = (_Float16)(vh * scl); fi[j] = (_Float16)(vi * scl);
            }
            a_hh[mt][kt] = fh; a_ih[mt][kt] = fi;
        }
    }

    // ---- stage x; init h_lds ----
    for (int k = tid; k < NB*TSEQ; k += 256)
        x_row[k >> 9][k & 511] = xin[(size_t)(b0 + (k >> 9))*TSEQ + (k & 511)];
    for (int k = tid; k < NLAY*2*16*72; k += 256)
        ((_Float16*)h_lds)[k] = (_Float16)(((k % 72) == HDIM) ? 1.f : 0.f);

    float hold[4][4];
#pragma unroll
    for (int m = 0; m < 4; ++m)
#pragma unroll
        for (int i = 0; i < 4; ++i) hold[m][i] = 0.f;
    __syncthreads();

    f16x8 bh0 = *(const f16x8*)&h_lds[lay][1][lb][8*lg];
    f16x8 bh1 = *(const f16x8*)&h_lds[lay][1][lb][32 + 8*lg];
    f16x8 bx0{}, bx1{};
    if (lay == 0) {
#pragma unroll
        for (int j = 0; j < 8; ++j) bx0[j] = (_Float16)0.f;
        if (lg == 0) { bx0[0] = (_Float16)x_row[lbc][0]; bx0[1] = (_Float16)1.f; }
    } else {
        bx0 = *(const f16x8*)&h_lds[lay-1][1][lb][8*lg];
        bx1 = *(const f16x8*)&h_lds[lay-1][1][lb][32 + 8*lg];
    }
    const f32x4 Z4 = {0.f, 0.f, 0.f, 0.f};

    for (int s = 0; s < TSEQ + NLAY - 1; ++s) {
        const int t = s - lay;
        if (t >= 0 && t < TSEQ) {
            f32x4 acc[NT], accx[4];
#pragma unroll
            for (int mt = 0; mt < NT; ++mt) acc[mt] = MFMA(a_hh[mt][0], bh0, Z4);
#pragma unroll
            for (int mt = 0; mt < NT; ++mt) acc[mt] = MFMA(a_hh[mt][1], bh1, acc[mt]);
#pragma unroll
            for (int mt = 0; mt < 8; ++mt)  acc[mt] = MFMA(a_ih[mt][0], bx0, acc[mt]);
#pragma unroll
            for (int m = 0; m < 4; ++m)     accx[m] = MFMA(a_ih[8+m][0], bx0, Z4);
            if (lay != 0) {
#pragma unroll
                for (int mt = 0; mt < 8; ++mt) acc[mt] = MFMA(a_ih[mt][1], bx1, acc[mt]);
#pragma unroll
                for (int m = 0; m < 4; ++m)    accx[m] = MFMA(a_ih[8+m][1], bx1, accx[m]);
            }

            // ---- r,z sigmoids: lane-pair shared (14 evals/lane, was 28) ----
#pragma unroll
            for (int mt = 0; mt < 8; ++mt) {
#pragma unroll
                for (int ip = 0; ip < 2; ++ip) {
                    if (((mt & 3) == 3) && ip == 1) continue;   // rows >= 50
                    const float v0 = acc[mt][2*ip], v1 = acc[mt][2*ip+1];
                    const float w  = swz8(v1);                  // partner's v1
                    const float s1_ = rcpf(1.f + ex2(lo ? v0 : w));
                    const float sb = swz8(s1_);                 // partner's result
                    acc[mt][2*ip]   = lo ? s1_ : sb;
                    acc[mt][2*ip+1] = lo ? sb  : s1_;
                }
            }

            // ---- n gate + h update: shared tanh (7 evals/lane, was 14) ----
            float hp[4][4];
#pragma unroll
            for (int m = 0; m < 4; ++m) {
#pragma unroll
                for (int ip = 0; ip < 2; ++ip) {
                    if (m == 3 && ip == 1) { hp[3][2] = 0.f; hp[3][3] = 0.f; continue; }
                    const int i0 = 2*ip, i1 = 2*ip + 1;
                    const float vp0 = accx[m][i0] + acc[m][i0] * acc[8+m][i0];
                    const float vp1 = accx[m][i1] + acc[m][i1] * acc[8+m][i1];
                    const float w   = swz8(vp1);
                    const float n_  = 1.f - 2.f*rcpf(ex2(lo ? vp0 : w) + 1.f);
                    const float nb  = swz8(n_);
                    const float n0  = lo ? n_ : nb;
                    const float n1  = lo ? nb : n_;
                    hp[m][i0] = fmaf(acc[4+m][i0], hold[m][i0] - n0, n0);
                    hp[m][i1] = fmaf(acc[4+m][i1], hold[m][i1] - n1, n1);
                    hold[m][i0] = hp[m][i0];
                    hold[m][i1] = hp[m][i1];
                }
            }

            // ---- publish h(t): 3x b64 + 1x b32 (lg==0) ----
            {
                _Float16* hrow = &h_lds[lay][s & 1][lb][0];
#pragma unroll
                for (int m = 0; m < 3; ++m) {
                    uint2 q; q.x = pk2(hp[m][0], hp[m][1]);
                             q.y = pk2(hp[m][2], hp[m][3]);
                    *(uint2*)&hrow[16*m + 4*lg] = q;
                }
                if (lg == 0)
                    *(unsigned*)&hrow[48] = pk2(hp[3][0], hp[3][1]);
            }
        }
        __syncthreads();   // h(t) for all layers published in buf[s&1]

        const int pb = s & 1;
        bh0 = *(const f16x8*)&h_lds[lay][pb][lb][8*lg];
        bh1 = *(const f16x8*)&h_lds[lay][pb][lb][32 + 8*lg];
        if (lay == 0) {
            const int tt = (s+1 < TSEQ) ? s+1 : TSEQ-1;
            if (lg == 0) bx0[0] = (_Float16)x_row[lbc][tt];
        } else {
            bx0 = *(const f16x8*)&h_lds[lay-1][pb][lb][8*lg];
            bx1 = *(const f16x8*)&h_lds[lay-1][pb][lb][32 + 8*lg];
        }
    }

    // ---- fused FC + sigmoid on layer-3 final h (s=514 -> parity 0) ----
    if (tid < NB) {
        float sacc = fcb[0];
#pragma unroll
        for (int j = 0; j < HDIM; ++j)
            sacc = fmaf((float)h_lds[NLAY-1][0][tid][j], fcw[j], sacc);
        out[b0 + tid] = rcpf(1.f + __expf(-sacc));
    }
}

extern "C" void kernel_launch(void* const* d_in, const int* in_sizes, int n_in,
                              void* d_out, int out_size, void* d_ws, size_t ws_size,
                              hipStream_t stream) {
    const float* x     = (const float*)d_in[0];
    const float* W_ih0 = (const float*)d_in[1];
    const float* W_hh0 = (const float*)d_in[2];
    const float* b_ih0 = (const float*)d_in[3];
    const float* b_hh0 = (const float*)d_in[4];
    const float* W_ih  = (const float*)d_in[5];
    const float* W_hh  = (const float*)d_in[6];
    const float* b_ih  = (const float*)d_in[7];
    const float* b_hh  = (const float*)d_in[8];
    const float* fc_w  = (const float*)d_in[9];
    const float* fc_b  = (const float*)d_in[10];
    float* out = (float*)d_out;

    dim3 grid(BATCH / NB), block(256);
    gru_fused1w<<<grid, block, 0, stream>>>(
        x, W_ih0, W_hh0, b_ih0, b_hh0,
        W_ih, W_hh, b_ih, b_hh, fc_w, fc_b, out);
}

// Round 15
// 596.111 us; speedup vs baseline: 1.3097x; 1.3097x over previous
//
#include <hip/hip_runtime.h>
#include <hip/hip_fp16.h>

#define HDIM  50
#define G3    150
#define TSEQ  512
#define BATCH 2048
#define NB    8        // real batches per block (MFMA cols 0..7; 8..15 mirror col 7)
#define NLAY  4
#define NT    12       // A-row tiles: 0-3 = r, 4-7 = z, 8-11 = n (50 real rows / 64)

typedef _Float16 f16x8 __attribute__((ext_vector_type(8)));
typedef float    f32x4 __attribute__((ext_vector_type(4)));

#define MFMA(a,b,c) __builtin_amdgcn_mfma_f32_16x16x32_f16((a),(b),(c),0,0,0)

static __device__ inline unsigned pk2(float a, float b) {
    return __builtin_bit_cast(unsigned, __builtin_amdgcn_cvt_pkrtz(a, b));
}
static __device__ inline float rcpf(float x) { return __builtin_amdgcn_rcpf(x); }

// raw v_exp_f32 (exp2), no ocml wrapper
#if __has_builtin(__builtin_amdgcn_exp2f)
static __device__ inline float ex2(float x) { return __builtin_amdgcn_exp2f(x); }
#else
static __device__ inline float ex2(float x) {
    float r; asm volatile("v_exp_f32 %0, %1" : "=v"(r) : "v"(x)); return r;
}
#endif
// lane xor-8 swap via DPP row_ror:8 (16-lane rows) -- full-rate VALU, no LDS pipe
static __device__ inline float dpp8(float x) {
    return __builtin_bit_cast(float, __builtin_amdgcn_mov_dpp(
        __builtin_bit_cast(int, x), 0x128, 0xf, 0xf, true));
}

// Weight pre-scaling folded at fragment load:
//   r,z columns * -log2(e):  sigmoid(g) = rcp(1 + exp2(acc))
//   n  columns * +2*log2(e): tanh(v)    = 1 - 2*rcp(exp2(acc) + 1)
#define SCL_RZ (-1.44269504f)
#define SCL_N  ( 2.88539008f)

// r10 skeleton (validated 621us): wave = layer, 3 gates in-wave tile-aligned,
// one barrier/step, parity double-buffered LDS handoff. This round: native
// exp2 + folded scales + lane-pair-shared evals transported by DPP (not LDS).
__global__ __launch_bounds__(256, 1)
void gru_fused1w(const float* __restrict__ xin,
                 const float* __restrict__ Wih0, const float* __restrict__ Whh0,
                 const float* __restrict__ bih0, const float* __restrict__ bhh0,
                 const float* __restrict__ WihL, const float* __restrict__ WhhL,
                 const float* __restrict__ bihL, const float* __restrict__ bhhL,
                 const float* __restrict__ fcw,  const float* __restrict__ fcb,
                 float* __restrict__ out)
{
    const int tid  = threadIdx.x;
    const int lay  = tid >> 6;
    const int lane = tid & 63;
    const int lb   = lane & 15;
    const int lg   = lane >> 4;
    const int b0   = blockIdx.x * NB;
    const int lbc  = (lb < NB) ? lb : (NB - 1);
    const bool lo  = (lb < 8);

    __shared__ __align__(16) _Float16 h_lds[NLAY][2][16][72];  // k=50 = const 1.0
    __shared__ float x_row[NB][516];

    const float* Wih = (lay==0) ? Wih0 : WihL + (size_t)(lay-1)*G3*HDIM;
    const float* Whh = (lay==0) ? Whh0 : WhhL + (size_t)(lay-1)*G3*HDIM;
    const float* bih = (lay==0) ? bih0 : bihL + (lay-1)*G3;
    const float* bhh = (lay==0) ? bhh0 : bhhL + (lay-1)*G3;

    // ---- A fragments; biases folded at k==50; transcendental scale folded ----
    f16x8 a_hh[NT][2], a_ih[NT][2];
#pragma unroll
    for (int mt = 0; mt < NT; ++mt) {
        const int  ur = (mt & 3)*16 + lb;
        const bool rv = ur < HDIM;
        const int  gr = 50*(mt >> 2) + (rv ? ur : 0);
        const float scl = (mt < 8) ? SCL_RZ : SCL_N;
#pragma unroll
        for (int kt = 0; kt < 2; ++kt) {
            f16x8 fh, fi;
#pragma unroll
            for (int j = 0; j < 8; ++j) {
                const int k = 32*kt + 8*lg + j;
                float vh = 0.f, vi = 0.f;
                if (rv) {
                    if (k < HDIM)       vh = Whh[gr*HDIM + k];
                    else if (k == HDIM) vh = bhh[gr];
                    if (lay == 0) {
                        if (kt == 0 && k == 0)      vi = Wih[gr];
                        else if (kt == 0 && k == 1) vi = bih[gr];
                    } else {
                        if (k < HDIM)       vi = Wih[gr*HDIM + k];
                        else if (k == HDIM) vi = bih[gr];
                    }
                }
                fh[j] = (_Float16)(vh * scl); fi[j] = (_Float16)(vi * scl);
            }
            a_hh[mt][kt] = fh; a_ih[mt][kt] = fi;
        }
    }

    // ---- stage x; init h_lds ----
    for (int k = tid; k < NB*TSEQ; k += 256)
        x_row[k >> 9][k & 511] = xin[(size_t)(b0 + (k >> 9))*TSEQ + (k & 511)];
    for (int k = tid; k < NLAY*2*16*72; k += 256)
        ((_Float16*)h_lds)[k] = (_Float16)(((k % 72) == HDIM) ? 1.f : 0.f);

    float hold[4][4];
#pragma unroll
    for (int m = 0; m < 4; ++m)
#pragma unroll
        for (int i = 0; i < 4; ++i) hold[m][i] = 0.f;
    __syncthreads();

    f16x8 bh0 = *(const f16x8*)&h_lds[lay][1][lb][8*lg];
    f16x8 bh1 = *(const f16x8*)&h_lds[lay][1][lb][32 + 8*lg];
    f16x8 bx0{}, bx1{};
    if (lay == 0) {
#pragma unroll
        for (int j = 0; j < 8; ++j) bx0[j] = (_Float16)0.f;
        if (lg == 0) { bx0[0] = (_Float16)x_row[lbc][0]; bx0[1] = (_Float16)1.f; }
    } else {
        bx0 = *(const f16x8*)&h_lds[lay-1][1][lb][8*lg];
        bx1 = *(const f16x8*)&h_lds[lay-1][1][lb][32 + 8*lg];
    }
    const f32x4 Z4 = {0.f, 0.f, 0.f, 0.f};

    for (int s = 0; s < TSEQ + NLAY - 1; ++s) {
        const int t = s - lay;
        if (t >= 0 && t < TSEQ) {
            f32x4 acc[NT], accx[4];
#pragma unroll
            for (int mt = 0; mt < NT; ++mt) acc[mt] = MFMA(a_hh[mt][0], bh0, Z4);
#pragma unroll
            for (int mt = 0; mt < NT; ++mt) acc[mt] = MFMA(a_hh[mt][1], bh1, acc[mt]);
#pragma unroll
            for (int mt = 0; mt < 8; ++mt)  acc[mt] = MFMA(a_ih[mt][0], bx0, acc[mt]);
#pragma unroll
            for (int m = 0; m < 4; ++m)     accx[m] = MFMA(a_ih[8+m][0], bx0, Z4);
            if (lay != 0) {
#pragma unroll
                for (int mt = 0; mt < 8; ++mt) acc[mt] = MFMA(a_ih[mt][1], bx1, acc[mt]);
#pragma unroll
                for (int m = 0; m < 4; ++m)    accx[m] = MFMA(a_ih[8+m][1], bx1, accx[m]);
            }

            // ---- r,z sigmoids: lane-pair shared via DPP (14 evals/lane) ----
#pragma unroll
            for (int mt = 0; mt < 8; ++mt) {
#pragma unroll
                for (int ip = 0; ip < 2; ++ip) {
                    if (((mt & 3) == 3) && ip == 1) continue;   // rows >= 50
                    const float v0 = acc[mt][2*ip], v1 = acc[mt][2*ip+1];
                    const float w  = dpp8(v1);                  // partner's v1
                    const float sg = rcpf(1.f + ex2(lo ? v0 : w));
                    const float sb = dpp8(sg);                  // partner's result
                    acc[mt][2*ip]   = lo ? sg : sb;
                    acc[mt][2*ip+1] = lo ? sb : sg;
                }
            }

            // ---- n gate + h update: shared tanh via DPP (7 evals/lane) ----
            float hp[4][4];
#pragma unroll
            for (int m = 0; m < 4; ++m) {
#pragma unroll
                for (int ip = 0; ip < 2; ++ip) {
                    if (m == 3 && ip == 1) { hp[3][2] = 0.f; hp[3][3] = 0.f; continue; }
                    const int i0 = 2*ip, i1 = 2*ip + 1;
                    const float vp0 = accx[m][i0] + acc[m][i0] * acc[8+m][i0];
                    const float vp1 = accx[m][i1] + acc[m][i1] * acc[8+m][i1];
                    const float w   = dpp8(vp1);
                    const float n_  = 1.f - 2.f*rcpf(ex2(lo ? vp0 : w) + 1.f);
                    const float nb  = dpp8(n_);
                    const float n0  = lo ? n_ : nb;
                    const float n1  = lo ? nb : n_;
                    hp[m][i0] = fmaf(acc[4+m][i0], hold[m][i0] - n0, n0);
                    hp[m][i1] = fmaf(acc[4+m][i1], hold[m][i1] - n1, n1);
                    hold[m][i0] = hp[m][i0];
                    hold[m][i1] = hp[m][i1];
                }
            }

            // ---- publish h(t): 3x b64 + 1x b32 (lg==0) ----
            {
                _Float16* hrow = &h_lds[lay][s & 1][lb][0];
#pragma unroll
                for (int m = 0; m < 3; ++m) {
                    uint2 q; q.x = pk2(hp[m][0], hp[m][1]);
                             q.y = pk2(hp[m][2], hp[m][3]);
                    *(uint2*)&hrow[16*m + 4*lg] = q;
                }
                if (lg == 0)
                    *(unsigned*)&hrow[48] = pk2(hp[3][0], hp[3][1]);
            }
        }
        __syncthreads();   // h(t) for all layers published in buf[s&1]

        const int pb = s & 1;
        bh0 = *(const f16x8*)&h_lds[lay][pb][lb][8*lg];
        bh1 = *(const f16x8*)&h_lds[lay][pb][lb][32 + 8*lg];
        if (lay == 0) {
            const int tt = (s+1 < TSEQ) ? s+1 : TSEQ-1;
            if (lg == 0) bx0[0] = (_Float16)x_row[lbc][tt];
        } else {
            bx0 = *(const f16x8*)&h_lds[lay-1][pb][lb][8*lg];
            bx1 = *(const f16x8*)&h_lds[lay-1][pb][lb][32 + 8*lg];
        }
    }

    // ---- fused FC + sigmoid on layer-3 final h (s=514 -> parity 0) ----
    if (tid < NB) {
        float sacc = fcb[0];
#pragma unroll
        for (int j = 0; j < HDIM; ++j)
            sacc = fmaf((float)h_lds[NLAY-1][0][tid][j], fcw[j], sacc);
        out[b0 + tid] = rcpf(1.f + __expf(-sacc));
    }
}

extern "C" void kernel_launch(void* const* d_in, const int* in_sizes, int n_in,
                              void* d_out, int out_size, void* d_ws, size_t ws_size,
                              hipStream_t stream) {
    const float* x     = (const float*)d_in[0];
    const float* W_ih0 = (const float*)d_in[1];
    const float* W_hh0 = (const float*)d_in[2];
    const float* b_ih0 = (const float*)d_in[3];
    const float* b_hh0 = (const float*)d_in[4];
    const float* W_ih  = (const float*)d_in[5];
    const float* W_hh  = (const float*)d_in[6];
    const float* b_ih  = (const float*)d_in[7];
    const float* b_hh  = (const float*)d_in[8];
    const float* fc_w  = (const float*)d_in[9];
    const float* fc_b  = (const float*)d_in[10];
    float* out = (float*)d_out;

    dim3 grid(BATCH / NB), block(256);
    gru_fused1w<<<grid, block, 0, stream>>>(
        x, W_ih0, W_hh0, b_ih0, b_hh0,
        W_ih, W_hh, b_ih, b_hh, fc_w, fc_b, out);
}

// Round 16
// 589.027 us; speedup vs baseline: 1.3255x; 1.0120x over previous
//
#include <hip/hip_runtime.h>
#include <hip/hip_fp16.h>

#define HDIM  50
#define G3    150
#define TSEQ  512
#define BATCH 2048
#define NB    8        // real batches per block (MFMA cols 0..7; 8..15 mirror col 7)
#define NLAY  4
#define NT    12       // A-row tiles: 0-3 = r, 4-7 = z, 8-11 = n (50 real rows / 64)

typedef _Float16 f16x8 __attribute__((ext_vector_type(8)));
typedef float    f32x4 __attribute__((ext_vector_type(4)));

#define MFMA(a,b,c) __builtin_amdgcn_mfma_f32_16x16x32_f16((a),(b),(c),0,0,0)

static __device__ inline unsigned pk2(float a, float b) {
    return __builtin_bit_cast(unsigned, __builtin_amdgcn_cvt_pkrtz(a, b));
}
static __device__ inline float rcpf(float x) { return __builtin_amdgcn_rcpf(x); }

// raw v_exp_f32 (exp2), no ocml wrapper
#if __has_builtin(__builtin_amdgcn_exp2f)
static __device__ inline float ex2(float x) { return __builtin_amdgcn_exp2f(x); }
#else
static __device__ inline float ex2(float x) {
    float r; asm volatile("v_exp_f32 %0, %1" : "=v"(r) : "v"(x)); return r;
}
#endif
// lane xor-8 swap via DPP row_ror:8 (16-lane rows) -- full-rate VALU
static __device__ inline float dpp8(float x) {
    return __builtin_bit_cast(float, __builtin_amdgcn_mov_dpp(
        __builtin_bit_cast(int, x), 0x128, 0xf, 0xf, true));
}

// Weight pre-scaling folded at fragment load:
//   r,z columns * -log2(e):  sigmoid(g) = rcp(1 + exp2(acc))
//   n  columns * +2*log2(e): tanh(v)    = 1 - 2*rcp(exp2(acc) + 1)
#define SCL_RZ (-1.44269504f)
#define SCL_N  ( 2.88539008f)

// r15 skeleton + 2-timestep supersteps (barriers 515 -> 259) over a ring-4
// h-slot buffer; own-h re-read immediately after publish (no barrier needed
// within a wave); both bx reads issued at superstep start so hh-MFMAs cover
// their latency.
__global__ __launch_bounds__(256, 1)
void gru_fused1w(const float* __restrict__ xin,
                 const float* __restrict__ Wih0, const float* __restrict__ Whh0,
                 const float* __restrict__ bih0, const float* __restrict__ bhh0,
                 const float* __restrict__ WihL, const float* __restrict__ WhhL,
                 const float* __restrict__ bihL, const float* __restrict__ bhhL,
                 const float* __restrict__ fcw,  const float* __restrict__ fcb,
                 float* __restrict__ out)
{
    const int tid  = threadIdx.x;
    const int lay  = tid >> 6;
    const int lane = tid & 63;
    const int lb   = lane & 15;
    const int lg   = lane >> 4;
    const int b0   = blockIdx.x * NB;
    const int lbc  = (lb < NB) ? lb : (NB - 1);
    const bool lo  = (lb < 8);

    // hsl[layer][slot][batchcol][k]: ring of 4 h snapshots; k=50 = const 1.0
    __shared__ __align__(16) _Float16 hsl[NLAY][4][16][72];
    __shared__ float x_row[NB][516];

    const float* Wih = (lay==0) ? Wih0 : WihL + (size_t)(lay-1)*G3*HDIM;
    const float* Whh = (lay==0) ? Whh0 : WhhL + (size_t)(lay-1)*G3*HDIM;
    const float* bih = (lay==0) ? bih0 : bihL + (lay-1)*G3;
    const float* bhh = (lay==0) ? bhh0 : bhhL + (lay-1)*G3;

    // ---- A fragments; biases folded at k==50; transcendental scale folded ----
    f16x8 a_hh[NT][2], a_ih[NT][2];
#pragma unroll
    for (int mt = 0; mt < NT; ++mt) {
        const int  ur = (mt & 3)*16 + lb;
        const bool rv = ur < HDIM;
        const int  gr = 50*(mt >> 2) + (rv ? ur : 0);
        const float scl = (mt < 8) ? SCL_RZ : SCL_N;
#pragma unroll
        for (int kt = 0; kt < 2; ++kt) {
            f16x8 fh, fi;
#pragma unroll
            for (int j = 0; j < 8; ++j) {
                const int k = 32*kt + 8*lg + j;
                float vh = 0.f, vi = 0.f;
                if (rv) {
                    if (k < HDIM)       vh = Whh[gr*HDIM + k];
                    else if (k == HDIM) vh = bhh[gr];
                    if (lay == 0) {
                        if (kt == 0 && k == 0)      vi = Wih[gr];
                        else if (kt == 0 && k == 1) vi = bih[gr];
                    } else {
                        if (k < HDIM)       vi = Wih[gr*HDIM + k];
                        else if (k == HDIM) vi = bih[gr];
                    }
                }
                fh[j] = (_Float16)(vh * scl); fi[j] = (_Float16)(vi * scl);
            }
            a_hh[mt][kt] = fh; a_ih[mt][kt] = fi;
        }
    }

    // ---- stage x; init all 4 ring slots (h=0, bias slot 50 = 1.0) ----
    for (int k = tid; k < NB*TSEQ; k += 256)
        x_row[k >> 9][k & 511] = xin[(size_t)(b0 + (k >> 9))*TSEQ + (k & 511)];
    for (int k = tid; k < NLAY*4*16*72; k += 256)
        ((_Float16*)hsl)[k] = (_Float16)(((k % 72) == HDIM) ? 1.f : 0.f);

    float hold[4][4];
#pragma unroll
    for (int m = 0; m < 4; ++m)
#pragma unroll
        for (int i = 0; i < 4; ++i) hold[m][i] = 0.f;
    __syncthreads();

    // own h(-1) fragments from init slot 3
    f16x8 bh0 = *(const f16x8*)&hsl[lay][3][lb][8*lg];
    f16x8 bh1 = *(const f16x8*)&hsl[lay][3][lb][32 + 8*lg];
    const f32x4 Z4 = {0.f, 0.f, 0.f, 0.f};

    // one GRU timestep: consumes bh0/bh1 (+bx), publishes h(t) to slot t&3,
    // re-reads own bh for the next step (same-wave DS ordering, no barrier).
    auto STEP = [&](int t, f16x8 bxk0, f16x8 bxk1) {
        f32x4 acc[NT], accx[4];
#pragma unroll
        for (int mt = 0; mt < NT; ++mt) acc[mt] = MFMA(a_hh[mt][0], bh0, Z4);
#pragma unroll
        for (int mt = 0; mt < NT; ++mt) acc[mt] = MFMA(a_hh[mt][1], bh1, acc[mt]);
#pragma unroll
        for (int mt = 0; mt < 8; ++mt)  acc[mt] = MFMA(a_ih[mt][0], bxk0, acc[mt]);
#pragma unroll
        for (int m = 0; m < 4; ++m)     accx[m] = MFMA(a_ih[8+m][0], bxk0, Z4);
        if (lay != 0) {
#pragma unroll
            for (int mt = 0; mt < 8; ++mt) acc[mt] = MFMA(a_ih[mt][1], bxk1, acc[mt]);
#pragma unroll
            for (int m = 0; m < 4; ++m)    accx[m] = MFMA(a_ih[8+m][1], bxk1, accx[m]);
        }

        // r,z sigmoids: lane-pair shared via DPP (14 evals/lane)
#pragma unroll
        for (int mt = 0; mt < 8; ++mt) {
#pragma unroll
            for (int ip = 0; ip < 2; ++ip) {
                if (((mt & 3) == 3) && ip == 1) continue;   // rows >= 50
                const float v0 = acc[mt][2*ip], v1 = acc[mt][2*ip+1];
                const float w  = dpp8(v1);
                const float sg = rcpf(1.f + ex2(lo ? v0 : w));
                const float sb = dpp8(sg);
                acc[mt][2*ip]   = lo ? sg : sb;
                acc[mt][2*ip+1] = lo ? sb : sg;
            }
        }

        // n gate + h update: shared tanh via DPP (7 evals/lane)
        float hp[4][4];
#pragma unroll
        for (int m = 0; m < 4; ++m) {
#pragma unroll
            for (int ip = 0; ip < 2; ++ip) {
                if (m == 3 && ip == 1) { hp[3][2] = 0.f; hp[3][3] = 0.f; continue; }
                const int i0 = 2*ip, i1 = 2*ip + 1;
                const float vp0 = accx[m][i0] + acc[m][i0] * acc[8+m][i0];
                const float vp1 = accx[m][i1] + acc[m][i1] * acc[8+m][i1];
                const float w   = dpp8(vp1);
                const float n_  = 1.f - 2.f*rcpf(ex2(lo ? vp0 : w) + 1.f);
                const float nb  = dpp8(n_);
                const float n0  = lo ? n_ : nb;
                const float n1  = lo ? nb : n_;
                hp[m][i0] = fmaf(acc[4+m][i0], hold[m][i0] - n0, n0);
                hp[m][i1] = fmaf(acc[4+m][i1], hold[m][i1] - n1, n1);
                hold[m][i0] = hp[m][i0];
                hold[m][i1] = hp[m][i1];
            }
        }

        // publish h(t) to slot t&3, then immediately re-read own B-fragments
        {
            _Float16* hrow = &hsl[lay][t & 3][lb][0];
#pragma unroll
            for (int m = 0; m < 3; ++m) {
                uint2 q; q.x = pk2(hp[m][0], hp[m][1]);
                         q.y = pk2(hp[m][2], hp[m][3]);
                *(uint2*)&hrow[16*m + 4*lg] = q;
            }
            if (lg == 0)
                *(unsigned*)&hrow[48] = pk2(hp[3][0], hp[3][1]);
        }
        bh0 = *(const f16x8*)&hsl[lay][t & 3][lb][8*lg];
        bh1 = *(const f16x8*)&hsl[lay][t & 3][lb][32 + 8*lg];
    };

    // 259 supersteps, 2 timesteps each; one barrier per superstep
    for (int s = 0; s < TSEQ/2 + NLAY - 1; ++s) {
        if (s >= lay && s < lay + TSEQ/2) {
            const int t0 = 2*(s - lay);
            f16x8 bxa0{}, bxa1{}, bxb0{}, bxb1{};
            if (lay == 0) {
#pragma unroll
                for (int j = 0; j < 8; ++j) { bxa0[j] = (_Float16)0.f; bxb0[j] = (_Float16)0.f; }
                if (lg == 0) {
                    bxa0[0] = (_Float16)x_row[lbc][t0];     bxa0[1] = (_Float16)1.f;
                    bxb0[0] = (_Float16)x_row[lbc][t0 + 1]; bxb0[1] = (_Float16)1.f;
                }
            } else {
                const int sa = t0 & 3, sb = (t0 + 1) & 3;
                bxa0 = *(const f16x8*)&hsl[lay-1][sa][lb][8*lg];
                bxa1 = *(const f16x8*)&hsl[lay-1][sa][lb][32 + 8*lg];
                bxb0 = *(const f16x8*)&hsl[lay-1][sb][lb][8*lg];
                bxb1 = *(const f16x8*)&hsl[lay-1][sb][lb][32 + 8*lg];
            }
            STEP(t0,     bxa0, bxa1);
            STEP(t0 + 1, bxb0, bxb1);
        }
        __syncthreads();   // producers' slots (t0+2,t0+3)&3 never collide with
                           // consumers' (t0,t0+1)&3 -> one barrier suffices
    }

    // ---- fused FC + sigmoid on layer-3 final h (t=511 -> slot 3) ----
    if (tid < NB) {
        float sacc = fcb[0];
#pragma unroll
        for (int j = 0; j < HDIM; ++j)
            sacc = fmaf((float)hsl[NLAY-1][3][tid][j], fcw[j], sacc);
        out[b0 + tid] = rcpf(1.f + __expf(-sacc));
    }
}

extern "C" void kernel_launch(void* const* d_in, const int* in_sizes, int n_in,
                              void* d_out, int out_size, void* d_ws, size_t ws_size,
                              hipStream_t stream) {
    const float* x     = (const float*)d_in[0];
    const float* W_ih0 = (const float*)d_in[1];
    const float* W_hh0 = (const float*)d_in[2];
    const float* b_ih0 = (const float*)d_in[3];
    const float* b_hh0 = (const float*)d_in[4];
    const float* W_ih  = (const float*)d_in[5];
    const float* W_hh  = (const float*)d_in[6];
    const float* b_ih  = (const float*)d_in[7];
    const float* b_hh  = (const float*)d_in[8];
    const float* fc_w  = (const float*)d_in[9];
    const float* fc_b  = (const float*)d_in[10];
    float* out = (float*)d_out;

    dim3 grid(BATCH / NB), block(256);
    gru_fused1w<<<grid, block, 0, stream>>>(
        x, W_ih0, W_hh0, b_ih0, b_hh0,
        W_ih, W_hh, b_ih, b_hh, fc_w, fc_b, out);
}

// Round 17
// 534.938 us; speedup vs baseline: 1.4595x; 1.1011x over previous
//
#include <hip/hip_runtime.h>
#include <hip/hip_fp16.h>

#define HDIM  50
#define G3    150
#define TSEQ  512
#define BATCH 2048
#define NBC   16      // batch cols per block -- ALL real now
#define NLAY  4

typedef _Float16 f16x8 __attribute__((ext_vector_type(8)));
typedef float    f32x4 __attribute__((ext_vector_type(4)));

#define MFMA(a,b,c) __builtin_amdgcn_mfma_f32_16x16x32_f16((a),(b),(c),0,0,0)

static __device__ inline unsigned pk2(float a, float b) {
    return __builtin_bit_cast(unsigned, __builtin_amdgcn_cvt_pkrtz(a, b));
}
static __device__ inline float rcpf(float x) { return __builtin_amdgcn_rcpf(x); }

#if __has_builtin(__builtin_amdgcn_exp2f)
static __device__ inline float ex2(float x) { return __builtin_amdgcn_exp2f(x); }
#else
static __device__ inline float ex2(float x) {
    float r; asm volatile("v_exp_f32 %0, %1" : "=v"(r) : "v"(x)); return r;
}
#endif

// Weight pre-scaling folded at fragment load:
//   r,z columns * -log2(e):  sigmoid(g) = rcp(1 + exp2(acc))
//   n  columns * +2*log2(e): tanh(v)    = 1 - 2*rcp(exp2(acc) + 1)
#define SCL_RZ (-1.44269504f)
#define SCL_N  ( 2.88539008f)

// 8 waves/block: wave (lay, wm) owns rows [32*wm, 32*wm+32) of layer `lay`'s
// 3 gate blocks (2 16-row tiles per gate). 16 real batch cols; blocks i and
// i+128 duplicate (replaces the old mirror-col waste) -> 2 waves/SIMD so
// MFMA/DS/trans latencies overlap across waves. One barrier per step, parity
// double-buffered LDS handoff (r10-validated protocol).
__global__ __launch_bounds__(512, 2)
void gru_8w(const float* __restrict__ xin,
            const float* __restrict__ Wih0, const float* __restrict__ Whh0,
            const float* __restrict__ bih0, const float* __restrict__ bhh0,
            const float* __restrict__ WihL, const float* __restrict__ WhhL,
            const float* __restrict__ bihL, const float* __restrict__ bhhL,
            const float* __restrict__ fcw,  const float* __restrict__ fcb,
            float* __restrict__ out)
{
    const int tid  = threadIdx.x;
    const int wid  = tid >> 6;
    const int lay  = wid >> 1;         // 0..3
    const int wm   = wid & 1;          // M-half: rows [32*wm, 32*wm+32)
    const int lane = tid & 63;
    const int lb   = lane & 15;        // batch col (all real)
    const int lg   = lane >> 4;        // k-octet (B) / C row group
    const int b0   = (blockIdx.x & 127) * NBC;
    const bool wr  = (blockIdx.x < 128);   // only lower copy writes output

    __shared__ __align__(16) _Float16 hsl[NLAY][2][16][72];  // k=50 = const 1.0
    __shared__ float x_row[NBC][516];

    const float* Wih = (lay==0) ? Wih0 : WihL + (size_t)(lay-1)*G3*HDIM;
    const float* Whh = (lay==0) ? Whh0 : WhhL + (size_t)(lay-1)*G3*HDIM;
    const float* bih = (lay==0) ? bih0 : bihL + (lay-1)*G3;
    const float* bhh = (lay==0) ? bhh0 : bhhL + (lay-1)*G3;

    // ---- A fragments [gate][sub][kt]; biases folded at k==50; scales folded ----
    f16x8 a_hh[3][2][2], a_ih[3][2][2];
#pragma unroll
    for (int g = 0; g < 3; ++g) {
#pragma unroll
        for (int sub = 0; sub < 2; ++sub) {
            const int  ur = (2*wm + sub)*16 + lb;   // absolute row 0..63
            const bool rv = ur < HDIM;
            const int  gr = 50*g + (rv ? ur : 0);
            const float scl = (g < 2) ? SCL_RZ : SCL_N;
#pragma unroll
            for (int kt = 0; kt < 2; ++kt) {
                f16x8 fh, fi;
#pragma unroll
                for (int j = 0; j < 8; ++j) {
                    const int k = 32*kt + 8*lg + j;
                    float vh = 0.f, vi = 0.f;
                    if (rv) {
                        if (k < HDIM)       vh = Whh[gr*HDIM + k];
                        else if (k == HDIM) vh = bhh[gr];
                        if (lay == 0) {
                            if (kt == 0 && k == 0)      vi = Wih[gr];
                            else if (kt == 0 && k == 1) vi = bih[gr];
                        } else {
                            if (k < HDIM)       vi = Wih[gr*HDIM + k];
                            else if (k == HDIM) vi = bih[gr];
                        }
                    }
                    fh[j] = (_Float16)(vh * scl); fi[j] = (_Float16)(vi * scl);
                }
                a_hh[g][sub][kt] = fh; a_ih[g][sub][kt] = fi;
            }
        }
    }

    // ---- stage x; init h_lds (h=0, bias slot 50 = 1.0, both parities) ----
    for (int k = tid; k < NBC*TSEQ; k += 512)
        x_row[k >> 9][k & 511] = xin[(size_t)(b0 + (k >> 9))*TSEQ + (k & 511)];
    for (int k = tid; k < NLAY*2*16*72; k += 512)
        ((_Float16*)hsl)[k] = (_Float16)(((k % 72) == HDIM) ? 1.f : 0.f);

    float hold[2][4];                  // persistent h for this wave's 32 rows
#pragma unroll
    for (int sub = 0; sub < 2; ++sub)
#pragma unroll
        for (int i = 0; i < 4; ++i) hold[sub][i] = 0.f;
    __syncthreads();

    f16x8 bh0 = *(const f16x8*)&hsl[lay][1][lb][8*lg];
    f16x8 bh1 = *(const f16x8*)&hsl[lay][1][lb][32 + 8*lg];
    f16x8 bx0{}, bx1{};
    if (lay == 0) {
#pragma unroll
        for (int j = 0; j < 8; ++j) bx0[j] = (_Float16)0.f;
        if (lg == 0) { bx0[0] = (_Float16)x_row[lb][0]; bx0[1] = (_Float16)1.f; }
    } else {
        bx0 = *(const f16x8*)&hsl[lay-1][1][lb][8*lg];
        bx1 = *(const f16x8*)&hsl[lay-1][1][lb][32 + 8*lg];
    }
    const f32x4 Z4 = {0.f, 0.f, 0.f, 0.f};

    for (int s = 0; s < TSEQ + NLAY - 1; ++s) {
        const int t = s - lay;
        if (t >= 0 && t < TSEQ) {
            f32x4 acc[3][2], accx[2];
#pragma unroll
            for (int g = 0; g < 3; ++g)
#pragma unroll
                for (int sub = 0; sub < 2; ++sub)
                    acc[g][sub] = MFMA(a_hh[g][sub][0], bh0, Z4);
#pragma unroll
            for (int g = 0; g < 3; ++g)
#pragma unroll
                for (int sub = 0; sub < 2; ++sub)
                    acc[g][sub] = MFMA(a_hh[g][sub][1], bh1, acc[g][sub]);
#pragma unroll
            for (int g = 0; g < 2; ++g)
#pragma unroll
                for (int sub = 0; sub < 2; ++sub)
                    acc[g][sub] = MFMA(a_ih[g][sub][0], bx0, acc[g][sub]);
#pragma unroll
            for (int sub = 0; sub < 2; ++sub)
                accx[sub] = MFMA(a_ih[2][sub][0], bx0, Z4);
            if (lay != 0) {
#pragma unroll
                for (int g = 0; g < 2; ++g)
#pragma unroll
                    for (int sub = 0; sub < 2; ++sub)
                        acc[g][sub] = MFMA(a_ih[g][sub][1], bx1, acc[g][sub]);
#pragma unroll
                for (int sub = 0; sub < 2; ++sub)
                    accx[sub] = MFMA(a_ih[2][sub][1], bx1, accx[sub]);
            }

            // ---- r,z sigmoids (unshared; ~14 evals/lane, no DPP overhead) ----
#pragma unroll
            for (int g = 0; g < 2; ++g)
#pragma unroll
                for (int sub = 0; sub < 2; ++sub)
#pragma unroll
                    for (int i = 0; i < 4; ++i) {
                        if (wm == 1 && sub == 1 && i >= 2) continue;  // rows >= 50
                        acc[g][sub][i] = rcpf(1.f + ex2(acc[g][sub][i]));
                    }

            // ---- n gate + h update ----
            float hp[2][4];
#pragma unroll
            for (int sub = 0; sub < 2; ++sub)
#pragma unroll
                for (int i = 0; i < 4; ++i) {
                    if (wm == 1 && sub == 1 && i >= 2) { hp[sub][i] = 0.f; continue; }
                    const float r  = acc[0][sub][i];
                    const float z  = acc[1][sub][i];
                    const float vp = accx[sub][i] + r * acc[2][sub][i];  // pre-scaled
                    const float n  = 1.f - 2.f*rcpf(ex2(vp) + 1.f);
                    const float h  = fmaf(z, hold[sub][i] - n, n);       // (1-z)n + zh
                    hold[sub][i] = h;
                    hp[sub][i] = h;
                }

            // ---- publish this wave's rows [32wm, 32wm+32) of h(t) ----
            {
                _Float16* hrow = &hsl[lay][s & 1][lb][0];
#pragma unroll
                for (int sub = 0; sub < 2; ++sub) {
                    if (wm == 1 && sub == 1) {
                        if (lg == 0)   // rows 48,49 only
                            *(unsigned*)&hrow[48] = pk2(hp[1][0], hp[1][1]);
                    } else {
                        uint2 q; q.x = pk2(hp[sub][0], hp[sub][1]);
                                 q.y = pk2(hp[sub][2], hp[sub][3]);
                        *(uint2*)&hrow[16*(2*wm + sub) + 4*lg] = q;
                    }
                }
            }
        }
        __syncthreads();   // h(t) fully assembled in buf[s&1]

        const int pb = s & 1;
        bh0 = *(const f16x8*)&hsl[lay][pb][lb][8*lg];
        bh1 = *(const f16x8*)&hsl[lay][pb][lb][32 + 8*lg];
        if (lay == 0) {
            const int tt = (s+1 < TSEQ) ? s+1 : TSEQ-1;
            if (lg == 0) bx0[0] = (_Float16)x_row[lb][tt];
        } else {
            bx0 = *(const f16x8*)&hsl[lay-1][pb][lb][8*lg];
            bx1 = *(const f16x8*)&hsl[lay-1][pb][lb][32 + 8*lg];
        }
    }

    // ---- fused FC + sigmoid on layer-3 final h (s=514 -> parity 0) ----
    if (wr && tid < NBC) {
        float sacc = fcb[0];
#pragma unroll
        for (int j = 0; j < HDIM; ++j)
            sacc = fmaf((float)hsl[NLAY-1][0][tid][j], fcw[j], sacc);
        out[b0 + tid] = rcpf(1.f + __expf(-sacc));
    }
}

extern "C" void kernel_launch(void* const* d_in, const int* in_sizes, int n_in,
                              void* d_out, int out_size, void* d_ws, size_t ws_size,
                              hipStream_t stream) {
    const float* x     = (const float*)d_in[0];
    const float* W_ih0 = (const float*)d_in[1];
    const float* W_hh0 = (const float*)d_in[2];
    const float* b_ih0 = (const float*)d_in[3];
    const float* b_hh0 = (const float*)d_in[4];
    const float* W_ih  = (const float*)d_in[5];
    const float* W_hh  = (const float*)d_in[6];
    const float* b_ih  = (const float*)d_in[7];
    const float* b_hh  = (const float*)d_in[8];
    const float* fc_w  = (const float*)d_in[9];
    const float* fc_b  = (const float*)d_in[10];
    float* out = (float*)d_out;

    dim3 grid(256), block(512);   // blocks i and i+128 duplicate; i<128 writes
    gru_8w<<<grid, block, 0, stream>>>(
        x, W_ih0, W_hh0, b_ih0, b_hh0,
        W_ih, W_hh, b_ih, b_hh, fc_w, fc_b, out);
}